// Round 15
// baseline (253.047 us; speedup 1.0000x reference)
//
#include <hip/hip_runtime.h>
#include <hip/hip_bf16.h>

// TemporalAttention fused kernel for MI355X (gfx950), round 15.
// = R14 compute (best) with the two LDS-pressure fixes:
//  1. W staging via global_load_lds from R12's VERIFIED pre-swizzled layout
//     (linear LDS dest + baked global permutation + swizzled read, G21):
//     removes 64 ds_writes/thread + ~32 staging VGPRs.
//  2. Single 48KB W buffer -> LDS 80KB -> 2 blocks/CU (was 1). Per-ks:
//     {read frags; bar_lgkm; issue ks+1 gload; MFMA; syncthreads(vmcnt)}.
//     The per-ks drain stall is hidden by the co-resident second block.
// Theory: R14's wall = LDS-pipe instruction count (~420/thread ~ 14us/block)
// + zero cross-block overlap. This cuts instrs ~20% and doubles residency.

namespace {

constexpr int S_LEN = 64;
constexpr int DM    = 256;
constexpr int SD    = S_LEN * DM;
constexpr int QKV_UNITS = 8 * 768 * 4;   // 24576 16B-units in wqt

typedef float f32x4 __attribute__((ext_vector_type(4)));
typedef short s16x8 __attribute__((ext_vector_type(8)));

union BF2 { __hip_bfloat162 h; unsigned u; };
__device__ __forceinline__ unsigned pkbf2(float a, float b) {
  float2 t; t.x = a; t.y = b;
  BF2 cv; cv.h = __float22bfloat162_rn(t);
  return cv.u;
}

// lgkm-only block barrier (R11-verified): does NOT drain vmcnt.
__device__ __forceinline__ void bar_lgkm() {
  asm volatile("s_waitcnt lgkmcnt(0)" ::: "memory");
  __builtin_amdgcn_sched_barrier(0);
  __builtin_amdgcn_s_barrier();
  __builtin_amdgcn_sched_barrier(0);
}

// In-register fragment transpose (verified rounds 3-14).
__device__ __forceinline__ s16x8 xpose_frag(f32x4 a0, f32x4 a1, int c, int g) {
  const int src0 = ((g & 1) << 5) + c;
  const int src1 = src0 + 16;
  unsigned p00 = pkbf2(a0[0], a0[1]);
  unsigned p01 = pkbf2(a0[2], a0[3]);
  unsigned p10 = pkbf2(a1[0], a1[1]);
  unsigned p11 = pkbf2(a1[2], a1[3]);
  const bool hi = (g & 2) != 0;
  unsigned w0a = (unsigned)__shfl((int)p00, src0);
  unsigned w0b = (unsigned)__shfl((int)p10, src0);
  unsigned w1a = (unsigned)__shfl((int)p01, src0);
  unsigned w1b = (unsigned)__shfl((int)p11, src0);
  unsigned w2a = (unsigned)__shfl((int)p00, src1);
  unsigned w2b = (unsigned)__shfl((int)p10, src1);
  unsigned w3a = (unsigned)__shfl((int)p01, src1);
  unsigned w3b = (unsigned)__shfl((int)p11, src1);
  union { s16x8 v; unsigned u[4]; } r;
  r.u[0] = hi ? w0b : w0a;
  r.u[1] = hi ? w1b : w1a;
  r.u[2] = hi ? w2b : w2a;
  r.u[3] = hi ? w3b : w3a;
  return r.v;
}

// W LDS read addressing (verified R9/R11/R12): per-ks image [rows][32] bf16,
// 16B-unit swizzle u' = g ^ ((row>>1)&3) => 2-way aliasing (free, m136).
__device__ __forceinline__ int wswz(int row, int u) {
  return row * 32 + ((u ^ ((row >> 1) & 3)) << 3);
}

} // namespace

// ---- prep (R12-verified): f32 -> bf16, per-ks images, baked read-swizzle ----
// wqt unit (ks,row,u) holds W_qkv[row][ks*32 + (u^s)*8 .. +8], s=(row>>1)&3;
// wpt likewise. Linear unit index -> global_load_lds dest is linear.
__global__ void ta_prep_weights(const float* __restrict__ wqkv,
                                const float* __restrict__ wproj,
                                unsigned short* __restrict__ wsb) {
  const int o = blockIdx.x * 256 + (int)threadIdx.x;   // 16B-unit index
  const float* src;
  if (o < QKV_UNITS) {
    const int ks = o / 3072, rem = o - ks * 3072;
    const int row = rem >> 2, u = rem & 3;
    const int s = (row >> 1) & 3;
    src = wqkv + row * 256 + ks * 32 + ((u ^ s) << 3);
  } else {
    const int p = o - QKV_UNITS;
    const int ks = p >> 10, rem = p & 1023;
    const int row = rem >> 2, u = rem & 3;
    const int s = (row >> 1) & 3;
    src = wproj + row * 256 + ks * 32 + ((u ^ s) << 3);
  }
  f32x4 a = *(const f32x4*)src;
  f32x4 b = *(const f32x4*)(src + 4);
  *(uint4*)(wsb + (size_t)o * 8) =
      make_uint4(pkbf2(a[0], a[1]), pkbf2(a[2], a[3]),
                 pkbf2(b[0], b[1]), pkbf2(b[2], b[3]));
}

__global__ void __launch_bounds__(512, 2)
ta_fused_kernel(const float* __restrict__ x,
                const unsigned short* __restrict__ wqt,   // [8][768][4] units
                const float* __restrict__ bqkv,
                const unsigned short* __restrict__ wpt,   // [8][256][4] units
                const float* __restrict__ bproj,
                float* __restrict__ out)
{
  // LDS 80KB (40960 shorts):
  //  [0,16384)      xls[64][256] bf16 X (swizzled) -> att overlay
  //  [16384,40960)  W image (48KB single buffer, gload_lds-filled);
  //                 phaseC uses first 16KB; epilogue f32 [32][256] overlays it
  __shared__ __align__(16) unsigned short lds[40960];

  const int bn = blockIdx.x;
  const int tid = (int)threadIdx.x;
  const int w = tid >> 6;       // wave 0..7 = head
  const int l = tid & 63;
  const int g = l >> 4;
  const int c = l & 15;
  const int c7s = (c & 7) << 3;
  const int h = w;

  unsigned short* __restrict__ xls = lds;
  unsigned short* __restrict__ wb  = lds + 16384;

  const float* __restrict__ xb = x + (size_t)bn * SD;

  // ---- issue W[ks=0] image (async, zero-VGPR; overlaps X staging) ----
#pragma unroll
  for (int i = 0; i < 6; ++i) {
    const int n = i * 512 + tid;
    __builtin_amdgcn_global_load_lds(
        (const __attribute__((address_space(1))) unsigned int*)(wqt + (size_t)n * 8),
        (__attribute__((address_space(3))) unsigned int*)(wb + n * 8), 16, 0, 0);
  }

  // ---- stage X -> LDS bf16 (swizzled, NT loads; verified R6/R14) ----
#pragma unroll
  for (int it = 0; it < 4; ++it) {
    const int e = (it * 512 + tid) * 8;
    const int row = e >> 8;
    f32x4 a = __builtin_nontemporal_load((const f32x4*)(xb + e));
    f32x4 b = __builtin_nontemporal_load((const f32x4*)(xb + e + 4));
    union { s16x8 v; unsigned u[4]; } r;
    r.u[0] = pkbf2(a[0], a[1]); r.u[1] = pkbf2(a[2], a[3]);
    r.u[2] = pkbf2(b[0], b[1]); r.u[3] = pkbf2(b[2], b[3]);
    *(s16x8*)&xls[e ^ ((row & 7) << 3)] = r.v;
  }
  __syncthreads();   // X visible; W0 landed (vmcnt drained)

  // ---- merged Q/K/V sweep: 8 ks-steps, single W buffer ----
  f32x4 aq[2][4], ak[2][4], av[4][2];
#pragma unroll
  for (int t = 0; t < 2; ++t)
#pragma unroll
    for (int nj = 0; nj < 4; ++nj) {
      aq[t][nj] = f32x4{0.f, 0.f, 0.f, 0.f};
      ak[t][nj] = f32x4{0.f, 0.f, 0.f, 0.f};
    }
#pragma unroll
  for (int mt = 0; mt < 4; ++mt)
#pragma unroll
    for (int t = 0; t < 2; ++t) av[mt][t] = f32x4{0.f, 0.f, 0.f, 0.f};

#pragma unroll
  for (int ks = 0; ks < 8; ++ks) {
    // read this ks's W fragments into registers
    s16x8 awq[2], awk[2], awv[2];
#pragma unroll
    for (int t = 0; t < 2; ++t) {
      awq[t] = *(const s16x8*)&wb[wswz((2 * h + t) * 16 + c, g)];
      awk[t] = *(const s16x8*)&wb[wswz(256 + 32 * h + 16 * t + c, g)];
      awv[t] = *(const s16x8*)&wb[wswz(512 + 32 * h + 16 * t + c, g)];
    }
    bar_lgkm();                       // all waves' W reads retired
    if (ks < 7) {                     // refill buffer for ks+1 (async)
#pragma unroll
      for (int i = 0; i < 6; ++i) {
        const int n = i * 512 + tid;
        __builtin_amdgcn_global_load_lds(
            (const __attribute__((address_space(1))) unsigned int*)(wqt + (size_t)((ks + 1) * 3072 + n) * 8),
            (__attribute__((address_space(3))) unsigned int*)(wb + n * 8), 16, 0, 0);
      }
    }
    const int kof = ks * 32 + g * 8;
    s16x8 bx[4];
#pragma unroll
    for (int nj = 0; nj < 4; ++nj) {
      const int row = 16 * nj + c;
      bx[nj] = *(const s16x8*)&xls[(row * 256 + kof) ^ c7s];
    }
#pragma unroll
    for (int t = 0; t < 2; ++t)
#pragma unroll
      for (int nj = 0; nj < 4; ++nj) {
        aq[t][nj] = __builtin_amdgcn_mfma_f32_16x16x32_bf16(awq[t], bx[nj], aq[t][nj], 0, 0, 0);
        ak[t][nj] = __builtin_amdgcn_mfma_f32_16x16x32_bf16(awk[t], bx[nj], ak[t][nj], 0, 0, 0);
        av[nj][t] = __builtin_amdgcn_mfma_f32_16x16x32_bf16(bx[nj], awv[t], av[nj][t], 0, 0, 0);
      }
    __syncthreads();                  // vmcnt drained: ks+1 image landed
  }

  // ---- issue phaseC W[0] image (lands during the attention middle) ----
#pragma unroll
  for (int i = 0; i < 2; ++i) {
    const int n = i * 512 + tid;
    __builtin_amdgcn_global_load_lds(
        (const __attribute__((address_space(1))) unsigned int*)(wpt + (size_t)n * 8),
        (__attribute__((address_space(3))) unsigned int*)(wb + n * 8), 16, 0, 0);
  }

  // ---- biases ----
#pragma unroll
  for (int t = 0; t < 2; ++t) {
    f32x4 bq = *(const f32x4*)(bqkv + (2 * h + t) * 16 + 4 * g);
    f32x4 bk = *(const f32x4*)(bqkv + 256 + 32 * h + 16 * t + 4 * g);
#pragma unroll
    for (int nj = 0; nj < 4; ++nj) {
      aq[t][nj] += bq;
      ak[t][nj] += bk;
    }
  }
  {
    const float bv0 = bqkv[512 + 32 * h + c];
    const float bv1 = bqkv[512 + 32 * h + 16 + c];
#pragma unroll
    for (int mt = 0; mt < 4; ++mt)
#pragma unroll
      for (int r = 0; r < 4; ++r) {
        av[mt][0][r] += bv0;
        av[mt][1][r] += bv1;
      }
  }

  // ---- Q,K fragments (in-register transpose) ----
  s16x8 qa[4], ka[4];
#pragma unroll
  for (int i = 0; i < 4; ++i) {
    qa[i] = xpose_frag(aq[0][i], aq[1][i], c, g);
    ka[i] = xpose_frag(ak[0][i], ak[1][i], c, g);
  }

  // ---- S^T = K @ Q^T ----
  f32x4 sa[4][4];
#pragma unroll
  for (int ki = 0; ki < 4; ++ki)
#pragma unroll
    for (int qi = 0; qi < 4; ++qi) {
      f32x4 z = f32x4{0.f, 0.f, 0.f, 0.f};
      sa[ki][qi] = __builtin_amdgcn_mfma_f32_16x16x32_bf16(ka[ki], qa[qi], z, 0, 0, 0);
    }

  // ---- softmax over keys ----
  const float sc = 0.17677669529663687f * 1.4426950408889634f;
  float inv[4];
#pragma unroll
  for (int qi = 0; qi < 4; ++qi) {
    float m = sa[0][qi][0];
#pragma unroll
    for (int ki = 0; ki < 4; ++ki)
#pragma unroll
      for (int r = 0; r < 4; ++r) m = fmaxf(m, sa[ki][qi][r]);
    m = fmaxf(m, __shfl_xor(m, 16));
    m = fmaxf(m, __shfl_xor(m, 32));
    float s = 0.0f;
#pragma unroll
    for (int ki = 0; ki < 4; ++ki)
#pragma unroll
      for (int r = 0; r < 4; ++r) {
        float pv = exp2f((sa[ki][qi][r] - m) * sc);
        sa[ki][qi][r] = pv;
        s += pv;
      }
    s += __shfl_xor(s, 16);
    s += __shfl_xor(s, 32);
    inv[qi] = 1.0f / s;
  }

  // ---- P fragments ----
  s16x8 pa[4][2];
#pragma unroll
  for (int mi = 0; mi < 4; ++mi) {
    const float iv = inv[mi];
#pragma unroll
    for (int ks2 = 0; ks2 < 2; ++ks2) {
      f32x4 v0 = sa[2 * ks2][mi] * iv;
      f32x4 v1 = sa[2 * ks2 + 1][mi] * iv;
      pa[mi][ks2] = xpose_frag(v0, v1, c, g);
    }
  }

  // ---- V fragments ----
  s16x8 vb[2][2];
#pragma unroll
  for (int nd = 0; nd < 2; ++nd)
#pragma unroll
    for (int ks2 = 0; ks2 < 2; ++ks2)
      vb[nd][ks2] = xpose_frag(av[2 * ks2][nd], av[2 * ks2 + 1][nd], c, g);

  // ---- O = P @ V ----
  f32x4 oa[4][2];
#pragma unroll
  for (int mi = 0; mi < 4; ++mi)
#pragma unroll
    for (int nd = 0; nd < 2; ++nd) oa[mi][nd] = f32x4{0.f, 0.f, 0.f, 0.f};
#pragma unroll
  for (int ks2 = 0; ks2 < 2; ++ks2)
#pragma unroll
    for (int mi = 0; mi < 4; ++mi)
#pragma unroll
      for (int nd = 0; nd < 2; ++nd)
        oa[mi][nd] = __builtin_amdgcn_mfma_f32_16x16x32_bf16(pa[mi][ks2], vb[nd][ks2], oa[mi][nd], 0, 0, 0);

  unsigned obp[4][2][2];
#pragma unroll
  for (int mi = 0; mi < 4; ++mi)
#pragma unroll
    for (int nd = 0; nd < 2; ++nd) {
      obp[mi][nd][0] = pkbf2(oa[mi][nd][0], oa[mi][nd][1]);
      obp[mi][nd][1] = pkbf2(oa[mi][nd][2], oa[mi][nd][3]);
    }

  // ---- scatter att over X region (X reads done at last sweep barrier) ----
#pragma unroll
  for (int mi = 0; mi < 4; ++mi)
#pragma unroll
    for (int nd = 0; nd < 2; ++nd)
#pragma unroll
      for (int r = 0; r < 4; ++r) {
        const int q = 16 * mi + 4 * g + r;
        const int feat = h * 32 + 16 * nd + c;
        unsigned val = obp[mi][nd][r >> 1] >> (16 * (r & 1));
        xls[(q * 256 + feat) ^ ((q & 7) << 3)] = (unsigned short)val;
      }
  __syncthreads();   // att visible + phaseC W0 landed (vmcnt drained)

  // ---- Phase C: out^T = Wproj @ att^T, single W buffer ----
  f32x4 pacc[2][4];
#pragma unroll
  for (int ti = 0; ti < 2; ++ti)
#pragma unroll
    for (int nj = 0; nj < 4; ++nj) pacc[ti][nj] = f32x4{0.f, 0.f, 0.f, 0.f};

#pragma unroll
  for (int ks = 0; ks < 8; ++ks) {
    s16x8 aw[2];
#pragma unroll
    for (int ti = 0; ti < 2; ++ti)
      aw[ti] = *(const s16x8*)&wb[wswz((2 * w + ti) * 16 + c, g)];
    bar_lgkm();                       // all waves' aw reads retired
    if (ks < 7) {
#pragma unroll
      for (int i = 0; i < 2; ++i) {
        const int n = i * 512 + tid;
        __builtin_amdgcn_global_load_lds(
            (const __attribute__((address_space(1))) unsigned int*)(wpt + (size_t)((ks + 1) * 1024 + n) * 8),
            (__attribute__((address_space(3))) unsigned int*)(wb + n * 8), 16, 0, 0);
      }
    }
    const int kof = ks * 32 + 8 * g;
    s16x8 bx[4];
#pragma unroll
    for (int nj = 0; nj < 4; ++nj) {
      const int row = 16 * nj + c;
      bx[nj] = *(const s16x8*)&xls[(row * 256 + kof) ^ c7s];
    }
#pragma unroll
    for (int ti = 0; ti < 2; ++ti)
#pragma unroll
      for (int nj = 0; nj < 4; ++nj)
        pacc[ti][nj] = __builtin_amdgcn_mfma_f32_16x16x32_bf16(aw[ti], bx[nj], pacc[ti][nj], 0, 0, 0);
    __syncthreads();                  // ks+1 image landed
  }

  // ---- epilogue: two 32-row f32 halves overlay the W region; NT stores ----
  float* ldsf = (float*)wb;
  float* __restrict__ ob = out + (size_t)bn * SD;
#pragma unroll
  for (int H = 0; H < 2; ++H) {
#pragma unroll
    for (int ti = 0; ti < 2; ++ti) {
      const int e0 = (2 * w + ti) * 16 + 4 * g;
      f32x4 bp = *(const f32x4*)(bproj + e0);
#pragma unroll
      for (int nj = 2 * H; nj < 2 * H + 2; ++nj) {
        const int lr = 16 * (nj - 2 * H) + c;
        f32x4 v;
        v[0] = pacc[ti][nj][0] + bp[0];
        v[1] = pacc[ti][nj][1] + bp[1];
        v[2] = pacc[ti][nj][2] + bp[2];
        v[3] = pacc[ti][nj][3] + bp[3];
        *(f32x4*)&ldsf[(lr * 256 + e0) ^ ((lr & 7) << 2)] = v;
      }
    }
    bar_lgkm();
#pragma unroll
    for (int it = 0; it < 4; ++it) {
      const int i = (it * 512 + tid) * 4;
      const int lr = i >> 8;
      f32x4 v = *(const f32x4*)&ldsf[i ^ ((lr & 7) << 2)];
      __builtin_nontemporal_store(v, (f32x4*)(ob + H * 8192 + i));
    }
    if (H == 0) bar_lgkm();
  }
}

extern "C" void kernel_launch(void* const* d_in, const int* in_sizes, int n_in,
                              void* d_out, int out_size, void* d_ws, size_t ws_size,
                              hipStream_t stream) {
  (void)n_in; (void)ws_size; (void)out_size;
  const float* x     = (const float*)d_in[0];
  const float* wqkv  = (const float*)d_in[1];
  const float* bqkv  = (const float*)d_in[2];
  const float* wproj = (const float*)d_in[3];
  const float* bproj = (const float*)d_in[4];
  float* out = (float*)d_out;

  unsigned short* wsb = (unsigned short*)d_ws;
  const unsigned short* wqt = wsb;                   // [8][768][4] 16B-units
  const unsigned short* wpt = wsb + QKV_UNITS * 8;   // [8][256][4]

  // 32768 units / 256 per block = 128 blocks
  hipLaunchKernelGGL(ta_prep_weights, dim3(128), dim3(256), 0, stream, wqkv, wproj, wsb);

  const int bn_total = in_sizes[0] / SD;  // 2600
  hipLaunchKernelGGL(ta_fused_kernel, dim3(bn_total), dim3(512), 0, stream,
                     x, wqt, bqkv, wpt, bproj, out);
}

// Round 16
// 235.782 us; speedup vs baseline: 1.0732x; 1.0732x over previous
//
#include <hip/hip_runtime.h>
#include <hip/hip_bf16.h>

// TemporalAttention fused kernel for MI355X (gfx950), round 16.
// = Round 14 (best: 257us kernel) + O-TRANSPOSED PV:
//   ot[nd][mi] = mfma(vb, pa) instead of oa = mfma(pa, vb). A/B fragments
//   have identical (lane->row, elem->k) structure for 16x16x32, so vb/pa
//   swap roles directly; D layout (col=lane&15=q, row=4g+r=d) makes each
//   lane own 4 CONTIGUOUS att feats -> the att scatter becomes 8 ds_write_b64
//   (was 32 scalar u16 with same-dword lane collisions = the 12M
//   SQ_LDS_BANK_CONFLICT that has been flat since R6). -24 LDS instrs/thread.

namespace {

constexpr int S_LEN = 64;
constexpr int DM    = 256;
constexpr int SD    = S_LEN * DM;
constexpr int NQKV  = 3 * DM * DM;

typedef float f32x4 __attribute__((ext_vector_type(4)));
typedef short s16x8 __attribute__((ext_vector_type(8)));

union BF2 { __hip_bfloat162 h; unsigned u; };
__device__ __forceinline__ unsigned pkbf2(float a, float b) {
  float2 t; t.x = a; t.y = b;
  BF2 cv; cv.h = __float22bfloat162_rn(t);
  return cv.u;
}

// lgkm-only block barrier (R11-verified): does NOT drain vmcnt.
__device__ __forceinline__ void bar_lgkm() {
  asm volatile("s_waitcnt lgkmcnt(0)" ::: "memory");
  __builtin_amdgcn_sched_barrier(0);
  __builtin_amdgcn_s_barrier();
  __builtin_amdgcn_sched_barrier(0);
}

// In-register fragment transpose (verified rounds 3-15).
__device__ __forceinline__ s16x8 xpose_frag(f32x4 a0, f32x4 a1, int c, int g) {
  const int src0 = ((g & 1) << 5) + c;
  const int src1 = src0 + 16;
  unsigned p00 = pkbf2(a0[0], a0[1]);
  unsigned p01 = pkbf2(a0[2], a0[3]);
  unsigned p10 = pkbf2(a1[0], a1[1]);
  unsigned p11 = pkbf2(a1[2], a1[3]);
  const bool hi = (g & 2) != 0;
  unsigned w0a = (unsigned)__shfl((int)p00, src0);
  unsigned w0b = (unsigned)__shfl((int)p10, src0);
  unsigned w1a = (unsigned)__shfl((int)p01, src0);
  unsigned w1b = (unsigned)__shfl((int)p11, src0);
  unsigned w2a = (unsigned)__shfl((int)p00, src1);
  unsigned w2b = (unsigned)__shfl((int)p10, src1);
  unsigned w3a = (unsigned)__shfl((int)p01, src1);
  unsigned w3b = (unsigned)__shfl((int)p11, src1);
  union { s16x8 v; unsigned u[4]; } r;
  r.u[0] = hi ? w0b : w0a;
  r.u[1] = hi ? w1b : w1a;
  r.u[2] = hi ? w2b : w2a;
  r.u[3] = hi ? w3b : w3a;
  return r.v;
}

// Weight LDS addressing (verified R9/R11): per-ks image [rows][32 cols] bf16,
// 16B-unit swizzle u' = g ^ ((row>>1)&3) => 2-way aliasing (free, m136).
__device__ __forceinline__ int wswz(int row, int u) {
  return row * 32 + ((u ^ ((row >> 1) & 3)) << 3);
}

} // namespace

// ---- prep: f32 weights -> bf16 in workspace ----
__global__ void ta_prep_weights(const float* __restrict__ wqkv,
                                const float* __restrict__ wproj,
                                unsigned short* __restrict__ wsb) {
  const int i = (blockIdx.x * 256 + (int)threadIdx.x) * 4;
  f32x4 v = (i < NQKV) ? *(const f32x4*)(wqkv + i)
                       : *(const f32x4*)(wproj + (i - NQKV));
  unsigned u0 = pkbf2(v[0], v[1]);
  unsigned u1 = pkbf2(v[2], v[3]);
  *(uint2*)(wsb + i) = make_uint2(u0, u1);
}

__global__ void __launch_bounds__(512, 1)
ta_fused_kernel(const float* __restrict__ x,
                const unsigned short* __restrict__ wq_bf,   // [768][256] bf16
                const float* __restrict__ bqkv,
                const unsigned short* __restrict__ wp_bf,   // [256][256] bf16
                const float* __restrict__ bproj,
                float* __restrict__ out)
{
  // LDS 128KB (65536 shorts):
  //  [0,16384)      xls[64][256] bf16 X (swizzled) -> att overlay
  //  [16384,40960)  W stage buffer 0 (48KB: [768][32] per-ks image)
  //  [40960,65536)  W stage buffer 1
  //  epilogue: f32 [32][256] overlay on buffer-0 region
  __shared__ __align__(16) unsigned short lds[65536];

  const int bn = blockIdx.x;
  const int tid = (int)threadIdx.x;
  const int w = tid >> 6;       // wave 0..7 = head
  const int l = tid & 63;
  const int g = l >> 4;
  const int c = l & 15;
  const int c7s = (c & 7) << 3;
  const int h = w;

  unsigned short* __restrict__ xls = lds;
  unsigned short* wbuf[2] = { lds + 16384, lds + 40960 };

  const float* __restrict__ xb = x + (size_t)bn * SD;

  // ---- issue W[ks=0] staging loads (fly under X stage) ----
  s16x8 wst[6];
#pragma unroll
  for (int i = 0; i < 6; ++i) {
    const int idx = i * 512 + tid, row = idx >> 2, gl = idx & 3;
    wst[i] = *(const s16x8*)&wq_bf[row * 256 + 0 * 32 + gl * 8];
  }

  // ---- stage X -> LDS bf16 (swizzled; NT loads: don't thrash L2) ----
#pragma unroll
  for (int it = 0; it < 4; ++it) {
    const int e = (it * 512 + tid) * 8;
    const int row = e >> 8;
    f32x4 a = __builtin_nontemporal_load((const f32x4*)(xb + e));
    f32x4 b = __builtin_nontemporal_load((const f32x4*)(xb + e + 4));
    union { s16x8 v; unsigned u[4]; } r;
    r.u[0] = pkbf2(a[0], a[1]); r.u[1] = pkbf2(a[2], a[3]);
    r.u[2] = pkbf2(b[0], b[1]); r.u[3] = pkbf2(b[2], b[3]);
    *(s16x8*)&xls[e ^ ((row & 7) << 3)] = r.v;
  }
  bar_lgkm();                      // X visible; wst0 loads still in flight

  // ---- W prologue: write buf0 = W[0]; issue W[1] ----
#pragma unroll
  for (int i = 0; i < 6; ++i) {
    const int idx = i * 512 + tid, row = idx >> 2, gl = idx & 3;
    *(s16x8*)&wbuf[0][wswz(row, gl)] = wst[i];
  }
#pragma unroll
  for (int i = 0; i < 6; ++i) {
    const int idx = i * 512 + tid, row = idx >> 2, gl = idx & 3;
    wst[i] = *(const s16x8*)&wq_bf[row * 256 + 1 * 32 + gl * 8];
  }
  bar_lgkm();                      // buf0 ready; W1 loads in flight

  // ---- merged Q/K/V sweep: 8 ks-steps, lgkm-only barriers ----
  f32x4 aq[2][4], ak[2][4], av[4][2];
#pragma unroll
  for (int t = 0; t < 2; ++t)
#pragma unroll
    for (int nj = 0; nj < 4; ++nj) {
      aq[t][nj] = f32x4{0.f, 0.f, 0.f, 0.f};
      ak[t][nj] = f32x4{0.f, 0.f, 0.f, 0.f};
    }
#pragma unroll
  for (int mt = 0; mt < 4; ++mt)
#pragma unroll
    for (int t = 0; t < 2; ++t) av[mt][t] = f32x4{0.f, 0.f, 0.f, 0.f};

#pragma unroll
  for (int ks = 0; ks < 8; ++ks) {
    const unsigned short* wb = wbuf[ks & 1];
    const int kof = ks * 32 + g * 8;
    s16x8 bx[4];
#pragma unroll
    for (int nj = 0; nj < 4; ++nj) {
      const int row = 16 * nj + c;
      bx[nj] = *(const s16x8*)&xls[(row * 256 + kof) ^ c7s];
    }
#pragma unroll
    for (int t = 0; t < 2; ++t) {
      s16x8 awq = *(const s16x8*)&wb[wswz((2 * h + t) * 16 + c, g)];
      s16x8 awk = *(const s16x8*)&wb[wswz(256 + 32 * h + 16 * t + c, g)];
      s16x8 awv = *(const s16x8*)&wb[wswz(512 + 32 * h + 16 * t + c, g)];
#pragma unroll
      for (int nj = 0; nj < 4; ++nj) {
        aq[t][nj] = __builtin_amdgcn_mfma_f32_16x16x32_bf16(awq, bx[nj], aq[t][nj], 0, 0, 0);
        ak[t][nj] = __builtin_amdgcn_mfma_f32_16x16x32_bf16(awk, bx[nj], ak[t][nj], 0, 0, 0);
        av[nj][t] = __builtin_amdgcn_mfma_f32_16x16x32_bf16(bx[nj], awv, av[nj][t], 0, 0, 0);
      }
    }
    if (ks < 7) {   // write next buffer (counted vmcnt wait, not 0)
#pragma unroll
      for (int i = 0; i < 6; ++i) {
        const int idx = i * 512 + tid, row = idx >> 2, gl = idx & 3;
        *(s16x8*)&wbuf[(ks + 1) & 1][wswz(row, gl)] = wst[i];
      }
    }
    if (ks < 6) {   // issue loads for ks+2 (stay in flight across barrier)
#pragma unroll
      for (int i = 0; i < 6; ++i) {
        const int idx = i * 512 + tid, row = idx >> 2, gl = idx & 3;
        wst[i] = *(const s16x8*)&wq_bf[row * 256 + (ks + 2) * 32 + gl * 8];
      }
    }
    bar_lgkm();
  }

  // ---- issue phaseC W[0] loads early (fly under the attention middle) ----
  s16x8 pst[2];
#pragma unroll
  for (int i = 0; i < 2; ++i) {
    const int idx = i * 512 + tid, row = idx >> 2, gl = idx & 3;
    pst[i] = *(const s16x8*)&wp_bf[row * 256 + 0 * 32 + gl * 8];
  }

  // ---- biases ----
#pragma unroll
  for (int t = 0; t < 2; ++t) {
    f32x4 bq = *(const f32x4*)(bqkv + (2 * h + t) * 16 + 4 * g);
    f32x4 bk = *(const f32x4*)(bqkv + 256 + 32 * h + 16 * t + 4 * g);
#pragma unroll
    for (int nj = 0; nj < 4; ++nj) {
      aq[t][nj] += bq;
      ak[t][nj] += bk;
    }
  }
  {
    const float bv0 = bqkv[512 + 32 * h + c];
    const float bv1 = bqkv[512 + 32 * h + 16 + c];
#pragma unroll
    for (int mt = 0; mt < 4; ++mt)
#pragma unroll
      for (int r = 0; r < 4; ++r) {
        av[mt][0][r] += bv0;
        av[mt][1][r] += bv1;
      }
  }

  // ---- Q,K fragments (in-register transpose) ----
  s16x8 qa[4], ka[4];
#pragma unroll
  for (int i = 0; i < 4; ++i) {
    qa[i] = xpose_frag(aq[0][i], aq[1][i], c, g);
    ka[i] = xpose_frag(ak[0][i], ak[1][i], c, g);
  }

  // ---- S^T = K @ Q^T ----
  f32x4 sa[4][4];
#pragma unroll
  for (int ki = 0; ki < 4; ++ki)
#pragma unroll
    for (int qi = 0; qi < 4; ++qi) {
      f32x4 z = f32x4{0.f, 0.f, 0.f, 0.f};
      sa[ki][qi] = __builtin_amdgcn_mfma_f32_16x16x32_bf16(ka[ki], qa[qi], z, 0, 0, 0);
    }

  // ---- softmax over keys ----
  const float sc = 0.17677669529663687f * 1.4426950408889634f;
  float inv[4];
#pragma unroll
  for (int qi = 0; qi < 4; ++qi) {
    float m = sa[0][qi][0];
#pragma unroll
    for (int ki = 0; ki < 4; ++ki)
#pragma unroll
      for (int r = 0; r < 4; ++r) m = fmaxf(m, sa[ki][qi][r]);
    m = fmaxf(m, __shfl_xor(m, 16));
    m = fmaxf(m, __shfl_xor(m, 32));
    float s = 0.0f;
#pragma unroll
    for (int ki = 0; ki < 4; ++ki)
#pragma unroll
      for (int r = 0; r < 4; ++r) {
        float pv = exp2f((sa[ki][qi][r] - m) * sc);
        sa[ki][qi][r] = pv;
        s += pv;
      }
    s += __shfl_xor(s, 16);
    s += __shfl_xor(s, 32);
    inv[qi] = 1.0f / s;
  }

  // ---- P fragments ----
  s16x8 pa[4][2];
#pragma unroll
  for (int mi = 0; mi < 4; ++mi) {
    const float iv = inv[mi];
#pragma unroll
    for (int ks2 = 0; ks2 < 2; ++ks2) {
      f32x4 v0 = sa[2 * ks2][mi] * iv;
      f32x4 v1 = sa[2 * ks2 + 1][mi] * iv;
      pa[mi][ks2] = xpose_frag(v0, v1, c, g);
    }
  }

  // ---- V fragments ----
  s16x8 vb[2][2];
#pragma unroll
  for (int nd = 0; nd < 2; ++nd)
#pragma unroll
    for (int ks2 = 0; ks2 < 2; ++ks2)
      vb[nd][ks2] = xpose_frag(av[2 * ks2][nd], av[2 * ks2 + 1][nd], c, g);

  // ---- O^T = V^T @ P^T : ot[nd][mi], D(row=4g+r -> d, col=c -> q) ----
  // A=vb (lane c<->d, elems=keys), B=pa (lane c<->q, elems=keys): identical
  // fragment structure, swapped roles. Same MFMA count as before.
  f32x4 ot[2][4];
#pragma unroll
  for (int nd = 0; nd < 2; ++nd)
#pragma unroll
    for (int mi = 0; mi < 4; ++mi) ot[nd][mi] = f32x4{0.f, 0.f, 0.f, 0.f};
#pragma unroll
  for (int ks2 = 0; ks2 < 2; ++ks2)
#pragma unroll
    for (int nd = 0; nd < 2; ++nd)
#pragma unroll
      for (int mi = 0; mi < 4; ++mi)
        ot[nd][mi] = __builtin_amdgcn_mfma_f32_16x16x32_bf16(vb[nd][ks2], pa[mi][ks2], ot[nd][mi], 0, 0, 0);

  // pack: lane owns att[q = 16mi+c][feat = h*32 + 16nd + 4g .. +3]
  uint2 obp[2][4];
#pragma unroll
  for (int nd = 0; nd < 2; ++nd)
#pragma unroll
    for (int mi = 0; mi < 4; ++mi) {
      obp[nd][mi].x = pkbf2(ot[nd][mi][0], ot[nd][mi][1]);
      obp[nd][mi].y = pkbf2(ot[nd][mi][2], ot[nd][mi][3]);
    }

  // ---- scatter att over X region (vectorized b64, 2-way banks);
  //      stage phaseC buf0; one barrier ----
#pragma unroll
  for (int nd = 0; nd < 2; ++nd)
#pragma unroll
    for (int mi = 0; mi < 4; ++mi) {
      const int q = 16 * mi + c;
      const int feat = h * 32 + 16 * nd + 4 * g;
      *(uint2*)&xls[(q * 256 + feat) ^ c7s] = obp[nd][mi];   // q&7 == c&7
    }
#pragma unroll
  for (int i = 0; i < 2; ++i) {
    const int idx = i * 512 + tid, row = idx >> 2, gl = idx & 3;
    *(s16x8*)&wbuf[0][wswz(row, gl)] = pst[i];
  }
#pragma unroll
  for (int i = 0; i < 2; ++i) {
    const int idx = i * 512 + tid, row = idx >> 2, gl = idx & 3;
    pst[i] = *(const s16x8*)&wp_bf[row * 256 + 1 * 32 + gl * 8];
  }
  bar_lgkm();                      // att + phaseC buf0 visible; P1 in flight

  // ---- Phase C: out^T = Wproj @ att^T, weights from staged LDS ----
  f32x4 pacc[2][4];
#pragma unroll
  for (int ti = 0; ti < 2; ++ti)
#pragma unroll
    for (int nj = 0; nj < 4; ++nj) pacc[ti][nj] = f32x4{0.f, 0.f, 0.f, 0.f};

#pragma unroll
  for (int ks = 0; ks < 8; ++ks) {
    const unsigned short* wb = wbuf[ks & 1];
    const int kof = ks * 32 + 8 * g;
    s16x8 bx[4];
#pragma unroll
    for (int nj = 0; nj < 4; ++nj) {
      const int row = 16 * nj + c;
      bx[nj] = *(const s16x8*)&xls[(row * 256 + kof) ^ c7s];
    }
#pragma unroll
    for (int ti = 0; ti < 2; ++ti) {
      s16x8 aw = *(const s16x8*)&wb[wswz((2 * w + ti) * 16 + c, g)];
#pragma unroll
      for (int nj = 0; nj < 4; ++nj)
        pacc[ti][nj] = __builtin_amdgcn_mfma_f32_16x16x32_bf16(aw, bx[nj], pacc[ti][nj], 0, 0, 0);
    }
    if (ks < 7) {
#pragma unroll
      for (int i = 0; i < 2; ++i) {
        const int idx = i * 512 + tid, row = idx >> 2, gl = idx & 3;
        *(s16x8*)&wbuf[(ks + 1) & 1][wswz(row, gl)] = pst[i];
      }
    }
    if (ks < 6) {
#pragma unroll
      for (int i = 0; i < 2; ++i) {
        const int idx = i * 512 + tid, row = idx >> 2, gl = idx & 3;
        pst[i] = *(const s16x8*)&wp_bf[row * 256 + (ks + 2) * 32 + gl * 8];
      }
    }
    bar_lgkm();
  }

  // ---- epilogue: two 32-row f32 halves (overlay W buf0), NT stores ----
  float* ldsf = (float*)wbuf[0];
  float* __restrict__ ob = out + (size_t)bn * SD;
#pragma unroll
  for (int H = 0; H < 2; ++H) {
#pragma unroll
    for (int ti = 0; ti < 2; ++ti) {
      const int e0 = (2 * w + ti) * 16 + 4 * g;
      f32x4 bp = *(const f32x4*)(bproj + e0);
#pragma unroll
      for (int nj = 2 * H; nj < 2 * H + 2; ++nj) {
        const int lr = 16 * (nj - 2 * H) + c;
        f32x4 v;
        v[0] = pacc[ti][nj][0] + bp[0];
        v[1] = pacc[ti][nj][1] + bp[1];
        v[2] = pacc[ti][nj][2] + bp[2];
        v[3] = pacc[ti][nj][3] + bp[3];
        *(f32x4*)&ldsf[(lr * 256 + e0) ^ ((lr & 7) << 2)] = v;
      }
    }
    bar_lgkm();
#pragma unroll
    for (int it = 0; it < 4; ++it) {
      const int i = (it * 512 + tid) * 4;
      const int lr = i >> 8;
      f32x4 v = *(const f32x4*)&ldsf[i ^ ((lr & 7) << 2)];
      __builtin_nontemporal_store(v, (f32x4*)(ob + H * 8192 + i));
    }
    if (H == 0) bar_lgkm();
  }
}

extern "C" void kernel_launch(void* const* d_in, const int* in_sizes, int n_in,
                              void* d_out, int out_size, void* d_ws, size_t ws_size,
                              hipStream_t stream) {
  (void)n_in; (void)ws_size; (void)out_size;
  const float* x     = (const float*)d_in[0];
  const float* wqkv  = (const float*)d_in[1];
  const float* bqkv  = (const float*)d_in[2];
  const float* wproj = (const float*)d_in[3];
  const float* bproj = (const float*)d_in[4];
  float* out = (float*)d_out;

  unsigned short* wsb = (unsigned short*)d_ws;
  const unsigned short* wq_bf = wsb;
  const unsigned short* wp_bf = wsb + NQKV;

  hipLaunchKernelGGL(ta_prep_weights, dim3(256), dim3(256), 0, stream, wqkv, wproj, wsb);

  const int bn_total = in_sizes[0] / SD;  // 2600
  hipLaunchKernelGGL(ta_fused_kernel, dim3(bn_total), dim3(512), 0, stream,
                     x, wq_bf, bqkv, wp_bf, bproj, out);
}